// Round 5
// baseline (155.524 us; speedup 1.0000x reference)
//
#include <hip/hip_runtime.h>

// EncoderDecoderLSTM fused kernel for MI355X (gfx950).
//
// Math: state never updates, h0=c0=0  =>
//   gates = input @ (W_ih @ enc_W)^T + (W_ih @ enc_b + b_ih + b_hh)
//   f-gate is dead (multiplies c0=0). Only i,g,o needed (768 of 1024 rows).
//
// prep2 pre-scales fused weights so MFMA emits exp2-ready gate values:
//     i,o rows x (-log2 e),  g rows x (2 log2 e)
//   U = exp2(iv), E = exp2(gv), Uo = exp2(ov)         (f32 trans, full rate)
//   tanh(g) = 1 - 2*rcp(1+E)    <- clamp-free: E=inf -> rcp=0 -> tanh=1
//   c = tanh(g) * rcp(1+U)      (sigma(i); U=inf -> 0; all corners exact)
//   tanh(c) via degree-11 odd poly, |c|<1 -- evaluated in PACKED f16
//   h = sigma(o) * tanh(c)      (pk_mul f16; result IS the LDS store word)
//   out = h @ dec_W^T + dec_b
//
// Round-5 change (scheduling only, math bitwise identical): software-pipeline
// the LDS h-handoff one phase deep. Old: act -> ds_write -> asm lgkmcnt(0)
// -> ds_read -> decMFMA  (full-drain wait x16/wave = exposed LDS latency).
// New: each phase ds_reads the PREVIOUS phase's tile (written ~500 VALU-cyc
// ago; wave-internal DS is processed in issue order, so RAW is safe), then
// does activation, then the previous tile's dec MFMA. No inline-asm waits in
// the main loop -- compiler emits precise counted lgkmcnt. a2_prev carried
// across hc (+8 VGPR); epilogue drains the last tile.
//
// Round-1 post-mortem: denominator-merging NaN-poisons under saturation and
// its clamps+muls exceed the rcp savings -- keep per-value 2-rcp structure.
// Round-3: only 2048 unique t rows (future rows = copies of t=2047);
// 2048 blocks = exactly 8/CU, t0=2016 wave fans out the 64 duplicate rows.
// Round-4: packed-f16 poly tail (SIMD-32: f16x2 halves lane-cycles).
//
// prep2: block-per-row parallel weight fusion (768 rows, 32-iter loops).
// lstm_main: per-wave 32 rows, f16 MFMA 16x16x32; biases ride the MFMA C
//   operand; h packed -> 8B LDS writes; decoder MFMA from LDS.

typedef _Float16 f16x8 __attribute__((ext_vector_type(8)));
typedef _Float16 f16x4 __attribute__((ext_vector_type(4)));
typedef _Float16 f16x2 __attribute__((ext_vector_type(2)));
typedef float    f32x4 __attribute__((ext_vector_type(4)));
typedef float    f32x2 __attribute__((ext_vector_type(2)));
typedef __fp16   h16x2 __attribute__((ext_vector_type(2)));

#define T_IN 2048
#define TT   2112   // T + future_n
#define FIN  32
#define FOUT 32

// ws layout (bytes): Mb @0 (49152), fb @49152 (3072), decWb @52224 (16384)
#define WS_FB_OFF   49152
#define WS_DECW_OFF 52224

union PkU { h16x2 h; f16x2 f; unsigned u; };

__global__ __launch_bounds__(256) void prep2(
    const float* __restrict__ enc_W, const float* __restrict__ enc_b,
    const float* __restrict__ W_ih, const float* __restrict__ b_ih,
    const float* __restrict__ b_hh, const float* __restrict__ dec_W,
    _Float16* __restrict__ Mb, float* __restrict__ fb, _Float16* __restrict__ decWb) {
    const int blk = blockIdx.x;
    const int tid = threadIdx.x;
    if (blk < 768) {
        // row gg: 0-255 = i (sg=gg), 256-511 = g (sg=gg+256), 512-767 = o
        const int gg = blk, sg = gg + (gg >= 256 ? 256 : 0);
        // exp2-ready prescale: i,o rows * -log2(e); g rows * 2*log2(e)
        const float SCL = (gg >= 256 && gg < 512) ?  2.8853900817779268f
                                                  : -1.4426950408889634f;
        const float* wr = W_ih + (size_t)sg * 256;
        const int f = tid & 31, r8 = tid >> 5;
        float acc = 0.f;
#pragma unroll
        for (int k = 0; k < 32; ++k) {
            int r = r8 * 32 + k;
            acc = fmaf(wr[r], enc_W[r * 32 + f], acc);
        }
        __shared__ float red[256];
        __shared__ float redb[256];
        __shared__ float red2[32];
        red[tid]  = acc;
        redb[tid] = wr[tid] * enc_b[tid];
        __syncthreads();
        if (tid < 32) {
            float s = 0.f;
#pragma unroll
            for (int k = 0; k < 8; ++k) s += red[k * 32 + tid];
            Mb[gg * 32 + tid] = (_Float16)(s * SCL);
        } else if (tid >= 128 && tid < 160) {
            int t2 = tid - 128;
            float s2 = 0.f;
#pragma unroll
            for (int k = 0; k < 8; ++k) s2 += redb[t2 * 8 + k];
            red2[t2] = s2;
        }
        __syncthreads();
        if (tid == 0) {
            float t = b_ih[sg] + b_hh[sg];
#pragma unroll
            for (int k = 0; k < 32; ++k) t += red2[k];
            fb[gg] = t * SCL;
        }
    } else {
        // blocks 768..775: dec_W f32 -> f16 (8192 elems, 4/thread)
        int i = (blk - 768) * 1024 + tid * 4;
        f32x4 v = *(const f32x4*)(dec_W + i);
        f16x4 o;
#pragma unroll
        for (int j = 0; j < 4; ++j) o[j] = (_Float16)v[j];
        *(f16x4*)(decWb + i) = o;
    }
}

// Activation for a PAIR of adjacent h-values. f32 trans front-end,
// packed-f16 poly tail. Returns the packed f16x2 h as a u32 (LDS-ready).
__device__ __forceinline__ unsigned act_pair(f32x2 iv, f32x2 gv, f32x2 ov) {
    f32x2 U, E, Uo;
    U.x  = __builtin_amdgcn_exp2f(iv.x); U.y  = __builtin_amdgcn_exp2f(iv.y);
    E.x  = __builtin_amdgcn_exp2f(gv.x); E.y  = __builtin_amdgcn_exp2f(gv.y);
    Uo.x = __builtin_amdgcn_exp2f(ov.x); Uo.y = __builtin_amdgcn_exp2f(ov.y);
    f32x2 aU = U + 1.0f, aE = E + 1.0f, aUo = Uo + 1.0f;
    f32x2 rU, rE, rUo;
    rU.x  = __builtin_amdgcn_rcpf(aU.x);  rU.y  = __builtin_amdgcn_rcpf(aU.y);
    rE.x  = __builtin_amdgcn_rcpf(aE.x);  rE.y  = __builtin_amdgcn_rcpf(aE.y);
    rUo.x = __builtin_amdgcn_rcpf(aUo.x); rUo.y = __builtin_amdgcn_rcpf(aUo.y);
    f32x2 th = 1.0f - 2.0f * rE;      // tanh(g): all saturations exact
    f32x2 c  = th * rU;               // sigma(i)*tanh(g), |c|<1
    // ---- packed f16 tail ----
    PkU cu; cu.h = __builtin_amdgcn_cvt_pkrtz(c.x, c.y);
    PkU su; su.h = __builtin_amdgcn_cvt_pkrtz(rUo.x, rUo.y);   // sigma(o)
    f16x2 c16 = cu.f, so = su.f;
    f16x2 z  = c16 * c16;
    f16x2 cz = c16 * z;
    f16x2 P  = z * (_Float16)(-5.70498872745e-3f) + (_Float16)(2.06390887954e-2f);
    P = z * P + (_Float16)(-5.37397155531e-2f);
    P = z * P + (_Float16)(1.33314422036e-1f);
    P = z * P + (_Float16)(-3.33332819422e-1f);
    f16x2 tc = cz * P + c16;          // tanh(c)
    PkU r; r.f = so * tc;             // h = sigma(o)*tanh(c), already f16x2
    return r.u;
}

__global__ __launch_bounds__(256) void lstm_main(
    const float* __restrict__ in, const _Float16* __restrict__ Mb,
    const float* __restrict__ fb, const _Float16* __restrict__ decWb,
    const float* __restrict__ dec_b, float* __restrict__ out) {
    // per-wave LDS: h tile [16 t][40 f16] (pitch 40 -> 2-way bank alias = free)
    // [2] = ping-pong by phase parity (s)
    __shared__ _Float16 hbuf[4][2][16 * 40];

    const int lane = threadIdx.x & 63;
    const int w    = threadIdx.x >> 6;
    const int l16  = lane & 15;
    const int q    = lane >> 4;
    const int wave = blockIdx.x * 4 + w;      // 0..8191
    const int b    = wave >> 6;                // 64 waves per batch row
    const int t0   = (wave & 63) * 32;         // 0..2016 (unique rows only)

    // Input B-fragments: B[k=q*8+j][n=l16] = input[b][t][q*8+j]  (t < 2048)
    f16x8 bfr[2];
#pragma unroll
    for (int s = 0; s < 2; ++s) {
        int t  = t0 + s * 16 + l16;
        const float* p = in + ((size_t)(b * T_IN + t)) * FIN + q * 8;
        f32x4 u0 = *(const f32x4*)(p);
        f32x4 u1 = *(const f32x4*)(p + 4);
        f16x8 v;
#pragma unroll
        for (int j = 0; j < 4; ++j) { v[j] = (_Float16)u0[j]; v[4 + j] = (_Float16)u1[j]; }
        bfr[s] = v;
    }

    // decoder acc starts at dec_b (rides the MFMA C operand)
    f32x4 dacc[2][2];
#pragma unroll
    for (int ot = 0; ot < 2; ++ot) {
        f32x4 db = *(const f32x4*)(dec_b + ot * 16 + q * 4);
        dacc[0][ot] = db; dacc[1][ot] = db;
    }

    _Float16* hp0 = &hbuf[w][0][0];
    _Float16* hp1 = &hbuf[w][1][0];
    const int rdoff = l16 * 40 + q * 8;        // b2 fragment read offset

    f16x8 a2p[2];                              // a2 of previous hc (drain use)

    for (int hc = 0; hc < 8; ++hc) {
        const int hb = hc * 32;
        // Gate weight A-frags + bias C-frags
        f16x8 afr[3][2];
        f32x4 fbv[3][2];
#pragma unroll
        for (int gt = 0; gt < 3; ++gt)
#pragma unroll
            for (int X = 0; X < 2; ++X) {
                int grow = gt * 256 + hb + X * 16;
                afr[gt][X] = *(const f16x8*)(Mb + (size_t)(grow + l16) * 32 + q * 8);
                fbv[gt][X] = *(const f32x4*)(fb + grow + q * 4);
            }
        // Decoder A-frags: A2[m=ot*16+l16][k -> hid=hb+q*8+j]
        f16x8 a2c[2];
#pragma unroll
        for (int ot = 0; ot < 2; ++ot)
            a2c[ot] = *(const f16x8*)(decWb + (size_t)(ot * 16 + l16) * 256 + hb + q * 8);

        // ---------------- phase s=0 ----------------
        {
            f32x4 gi[2], gg[2], go[2];
#pragma unroll
            for (int X = 0; X < 2; ++X) {
                gi[X] = __builtin_amdgcn_mfma_f32_16x16x32_f16(afr[0][X], bfr[0], fbv[0][X], 0, 0, 0);
                gg[X] = __builtin_amdgcn_mfma_f32_16x16x32_f16(afr[1][X], bfr[0], fbv[1][X], 0, 0, 0);
                go[X] = __builtin_amdgcn_mfma_f32_16x16x32_f16(afr[2][X], bfr[0], fbv[2][X], 0, 0, 0);
            }
            f16x8 b2;                      // (hc-1, s=1) tile, written ~1 phase ago
            if (hc > 0) b2 = *(const f16x8*)(hp1 + rdoff);
#pragma unroll
            for (int X = 0; X < 2; ++X) {
                f32x2 i01 = { gi[X][0], gi[X][1] }, i23 = { gi[X][2], gi[X][3] };
                f32x2 g01 = { gg[X][0], gg[X][1] }, g23 = { gg[X][2], gg[X][3] };
                f32x2 o01 = { go[X][0], go[X][1] }, o23 = { go[X][2], go[X][3] };
                uint2 wv;
                wv.x = act_pair(i01, g01, o01);
                wv.y = act_pair(i23, g23, o23);
                *(uint2*)(hp0 + l16 * 40 + X * 16 + q * 4) = wv;
            }
            if (hc > 0) {
#pragma unroll
                for (int ot = 0; ot < 2; ++ot)
                    dacc[1][ot] = __builtin_amdgcn_mfma_f32_16x16x32_f16(a2p[ot], b2, dacc[1][ot], 0, 0, 0);
            }
        }

        // ---------------- phase s=1 ----------------
        {
            f32x4 gi[2], gg[2], go[2];
#pragma unroll
            for (int X = 0; X < 2; ++X) {
                gi[X] = __builtin_amdgcn_mfma_f32_16x16x32_f16(afr[0][X], bfr[1], fbv[0][X], 0, 0, 0);
                gg[X] = __builtin_amdgcn_mfma_f32_16x16x32_f16(afr[1][X], bfr[1], fbv[1][X], 0, 0, 0);
                go[X] = __builtin_amdgcn_mfma_f32_16x16x32_f16(afr[2][X], bfr[1], fbv[2][X], 0, 0, 0);
            }
            // (hc, s=0) tile: writes issued one activation-phase ago; wave-
            // internal DS is processed in issue order -> RAW safe, no fence.
            f16x8 b2 = *(const f16x8*)(hp0 + rdoff);
#pragma unroll
            for (int X = 0; X < 2; ++X) {
                f32x2 i01 = { gi[X][0], gi[X][1] }, i23 = { gi[X][2], gi[X][3] };
                f32x2 g01 = { gg[X][0], gg[X][1] }, g23 = { gg[X][2], gg[X][3] };
                f32x2 o01 = { go[X][0], go[X][1] }, o23 = { go[X][2], go[X][3] };
                uint2 wv;
                wv.x = act_pair(i01, g01, o01);
                wv.y = act_pair(i23, g23, o23);
                *(uint2*)(hp1 + l16 * 40 + X * 16 + q * 4) = wv;
            }
#pragma unroll
            for (int ot = 0; ot < 2; ++ot)
                dacc[0][ot] = __builtin_amdgcn_mfma_f32_16x16x32_f16(a2c[ot], b2, dacc[0][ot], 0, 0, 0);
        }

#pragma unroll
        for (int ot = 0; ot < 2; ++ot) a2p[ot] = a2c[ot];
    }

    // epilogue: drain (hc=7, s=1)
    {
        f16x8 b2 = *(const f16x8*)(hp1 + rdoff);
#pragma unroll
        for (int ot = 0; ot < 2; ++ot)
            dacc[1][ot] = __builtin_amdgcn_mfma_f32_16x16x32_f16(a2p[ot], b2, dacc[1][ot], 0, 0, 0);
    }

    // D2[od = ot*16 + 4q + r][t=l16] -> out[(b*TT+t)*32 + od], float4 per lane
#pragma unroll
    for (int s = 0; s < 2; ++s) {
        int t = t0 + s * 16 + l16;
        size_t ro = ((size_t)(b * TT + t)) * FOUT;
#pragma unroll
        for (int ot = 0; ot < 2; ++ot)
            *(f32x4*)(out + ro + ot * 16 + q * 4) = dacc[s][ot];
    }

    // Future rows 2048..2111 are copies of row 2047 (held by lanes l16==15
    // of the wave with t0==2016). Broadcast that row wave-internally via LDS,
    // then all 64 lanes fan the 64 duplicate rows out.
    if ((wave & 63) == 63) {
        float* fo = (float*)&hbuf[w][0][0];   // wave-private scratch, done with it
        if (l16 == 15) {
            *(f32x4*)(fo + q * 4)      = dacc[1][0];
            *(f32x4*)(fo + 16 + q * 4) = dacc[1][1];
        }
        asm volatile("s_waitcnt lgkmcnt(0)" ::: "memory");
        f32x4 r0 = *(const f32x4*)(fo + q * 4);
        f32x4 r1 = *(const f32x4*)(fo + 16 + q * 4);
#pragma unroll
        for (int fg = 0; fg < 4; ++fg) {
            int t = T_IN + fg * 16 + l16;
            size_t ro = ((size_t)(b * TT + t)) * FOUT;
            *(f32x4*)(out + ro + q * 4)      = r0;
            *(f32x4*)(out + ro + 16 + q * 4) = r1;
        }
    }
}

extern "C" void kernel_launch(void* const* d_in, const int* in_sizes, int n_in,
                              void* d_out, int out_size, void* d_ws, size_t ws_size,
                              hipStream_t stream) {
    const float* input = (const float*)d_in[0];
    const float* enc_W = (const float*)d_in[1];
    const float* enc_b = (const float*)d_in[2];
    const float* W_ih  = (const float*)d_in[3];
    // d_in[4] = W_hh: unused (h0 = 0 -> state_gates = b_hh only)
    const float* b_ih  = (const float*)d_in[5];
    const float* b_hh  = (const float*)d_in[6];
    const float* dec_W = (const float*)d_in[7];
    const float* dec_b = (const float*)d_in[8];
    // d_in[9] = future_n (fixed 64, baked into TT)

    _Float16* Mb    = (_Float16*)d_ws;
    float*    fb    = (float*)((char*)d_ws + WS_FB_OFF);
    _Float16* decWb = (_Float16*)((char*)d_ws + WS_DECW_OFF);
    float*    out   = (float*)d_out;

    prep2<<<776, 256, 0, stream>>>(enc_W, enc_b, W_ih, b_ih, b_hh, dec_W, Mb, fb, decWb);
    // 128 b * 2048 unique t rows / 32 rows-per-wave = 8192 waves; 4 waves/block
    // = 2048 blocks = exactly 8 blocks/CU (perfect balance)
    lstm_main<<<2048, 256, 0, stream>>>(input, Mb, fb, decWb, dec_b, out);
}

// Round 7
// 151.697 us; speedup vs baseline: 1.0252x; 1.0252x over previous
//
#include <hip/hip_runtime.h>

// EncoderDecoderLSTM fused kernel for MI355X (gfx950).
//
// Math: state never updates, h0=c0=0  =>
//   gates = input @ (W_ih @ enc_W)^T + (W_ih @ enc_b + b_ih + b_hh)
//   f-gate is dead (multiplies c0=0). Only i,g,o needed (768 of 1024 rows).
//
// prep2 pre-scales fused weights so MFMA emits exp2-ready gate values:
//     i,o rows x (-log2 e),  g rows x (2 log2 e)
//   U = exp2(iv), E = exp2(gv), Uo = exp2(ov)         (f32 trans, full rate)
//   tanh(g) = 1 - 2*rcp(1+E)    <- clamp-free: E=inf -> rcp=0 -> tanh=1
//   c = tanh(g) * rcp(1+U)      (sigma(i); U=inf -> 0; all corners exact)
//   tanh(c) via degree-11 odd poly, |c|<1 -- evaluated in PACKED f16
//   h = sigma(o) * tanh(c)
//   out = h @ dec_W^T + dec_b
//
// Round-6/7 change: ELIMINATE the LDS h-handoff. The dec MFMA sums over hid,
// so any permutation applied to BOTH decW's k-slots and h's k-slots is
// invariant. prep2 stores decWb with slot (q*8+j) <- hid (j<4 ? 4q+j
// : 16+4q+j-4) within each 32-hid block; then the gate-MFMA D-layout output
// (lane (l16,q) holds h[t=l16][X*16+4q+r]), packed in production order,
// IS the decoder B-fragment. Deletes 2 ds_write + 1 ds_read + 1 full
// lgkmcnt(0) drain per phase (x16/wave) and all LDS bank conflicts, at
// ZERO register cost (round-5 lesson: VGPR>64 cuts occupancy 8->6 w/SIMD).
// (Round-6 bench was an infra failure -- container died; resubmitting.)
//
// Round-1 post-mortem: denominator-merging NaN-poisons under saturation and
// its clamps+muls exceed the rcp savings -- keep per-value structure.
// Round-3: only 2048 unique t rows (future rows = copies of t=2047);
// 2048 blocks = exactly 8/CU, t0=2016 wave fans out the 64 duplicate rows.
// Round-4: packed-f16 poly tail (SIMD-32: f16x2 halves lane-cycles).
// Round-5: 1-deep pipeline REGRESSED (VGPR 64->80, occupancy -21%).
//
// prep2: block-per-row parallel weight fusion (768 rows, 32-iter loops).
// lstm_main: per-wave 32 rows, f16 MFMA 16x16x32; biases ride the MFMA C
//   operand; activation output feeds the decoder MFMA directly in registers.

typedef _Float16 f16x8 __attribute__((ext_vector_type(8)));
typedef _Float16 f16x4 __attribute__((ext_vector_type(4)));
typedef _Float16 f16x2 __attribute__((ext_vector_type(2)));
typedef float    f32x4 __attribute__((ext_vector_type(4)));
typedef float    f32x2 __attribute__((ext_vector_type(2)));
typedef __fp16   h16x2 __attribute__((ext_vector_type(2)));

#define T_IN 2048
#define TT   2112   // T + future_n
#define FIN  32
#define FOUT 32

// ws layout (bytes): Mb @0 (49152), fb @49152 (3072), decWb @52224 (16384)
#define WS_FB_OFF   49152
#define WS_DECW_OFF 52224

union PkU { h16x2 h; f16x2 f; unsigned u; };
union B2U { f16x8 v; unsigned u[4]; };

__global__ __launch_bounds__(256) void prep2(
    const float* __restrict__ enc_W, const float* __restrict__ enc_b,
    const float* __restrict__ W_ih, const float* __restrict__ b_ih,
    const float* __restrict__ b_hh, const float* __restrict__ dec_W,
    _Float16* __restrict__ Mb, float* __restrict__ fb, _Float16* __restrict__ decWb) {
    const int blk = blockIdx.x;
    const int tid = threadIdx.x;
    if (blk < 768) {
        // row gg: 0-255 = i (sg=gg), 256-511 = g (sg=gg+256), 512-767 = o
        const int gg = blk, sg = gg + (gg >= 256 ? 256 : 0);
        // exp2-ready prescale: i,o rows * -log2(e); g rows * 2*log2(e)
        const float SCL = (gg >= 256 && gg < 512) ?  2.8853900817779268f
                                                  : -1.4426950408889634f;
        const float* wr = W_ih + (size_t)sg * 256;
        const int f = tid & 31, r8 = tid >> 5;
        float acc = 0.f;
#pragma unroll
        for (int k = 0; k < 32; ++k) {
            int r = r8 * 32 + k;
            acc = fmaf(wr[r], enc_W[r * 32 + f], acc);
        }
        __shared__ float red[256];
        __shared__ float redb[256];
        __shared__ float red2[32];
        red[tid]  = acc;
        redb[tid] = wr[tid] * enc_b[tid];
        __syncthreads();
        if (tid < 32) {
            float s = 0.f;
#pragma unroll
            for (int k = 0; k < 8; ++k) s += red[k * 32 + tid];
            Mb[gg * 32 + tid] = (_Float16)(s * SCL);
        } else if (tid >= 128 && tid < 160) {
            int t2 = tid - 128;
            float s2 = 0.f;
#pragma unroll
            for (int k = 0; k < 8; ++k) s2 += redb[t2 * 8 + k];
            red2[t2] = s2;
        }
        __syncthreads();
        if (tid == 0) {
            float t = b_ih[sg] + b_hh[sg];
#pragma unroll
            for (int k = 0; k < 32; ++k) t += red2[k];
            fb[gg] = t * SCL;
        }
    } else {
        // blocks 768..775: dec_W f32 -> f16, PERMUTED within each 32-hid
        // block so the decoder B-operand is the activation output in its
        // natural register order: slot (q*8+j) <- hid (j<4 ? 4q+j
        // : 16+4q+j-4). Each thread's 4 slots map to 4 CONTIGUOUS source
        // hids, so the f32x4 load survives.
        int i  = (blk - 768) * 1024 + tid * 4;   // 4 consecutive slots
        int od = i >> 8, s = i & 255;
        int hb = s & 224, s32 = s & 31;
        int q  = s32 >> 3;
        int src = od * 256 + hb + 4 * q + ((s32 & 4) ? 16 : 0);
        f32x4 v = *(const f32x4*)(dec_W + src);
        f16x4 o;
#pragma unroll
        for (int j = 0; j < 4; ++j) o[j] = (_Float16)v[j];
        *(f16x4*)(decWb + i) = o;
    }
}

// Activation for a PAIR of adjacent h-values. f32 trans front-end,
// packed-f16 poly tail. Returns the packed f16x2 h as a u32.
__device__ __forceinline__ unsigned act_pair(f32x2 iv, f32x2 gv, f32x2 ov) {
    f32x2 U, E, Uo;
    U.x  = __builtin_amdgcn_exp2f(iv.x); U.y  = __builtin_amdgcn_exp2f(iv.y);
    E.x  = __builtin_amdgcn_exp2f(gv.x); E.y  = __builtin_amdgcn_exp2f(gv.y);
    Uo.x = __builtin_amdgcn_exp2f(ov.x); Uo.y = __builtin_amdgcn_exp2f(ov.y);
    f32x2 aU = U + 1.0f, aE = E + 1.0f, aUo = Uo + 1.0f;
    f32x2 rU, rE, rUo;
    rU.x  = __builtin_amdgcn_rcpf(aU.x);  rU.y  = __builtin_amdgcn_rcpf(aU.y);
    rE.x  = __builtin_amdgcn_rcpf(aE.x);  rE.y  = __builtin_amdgcn_rcpf(aE.y);
    rUo.x = __builtin_amdgcn_rcpf(aUo.x); rUo.y = __builtin_amdgcn_rcpf(aUo.y);
    f32x2 th = 1.0f - 2.0f * rE;      // tanh(g): all saturations exact
    f32x2 c  = th * rU;               // sigma(i)*tanh(g), |c|<1
    // ---- packed f16 tail ----
    PkU cu; cu.h = __builtin_amdgcn_cvt_pkrtz(c.x, c.y);
    PkU su; su.h = __builtin_amdgcn_cvt_pkrtz(rUo.x, rUo.y);   // sigma(o)
    f16x2 c16 = cu.f, so = su.f;
    f16x2 z  = c16 * c16;
    f16x2 cz = c16 * z;
    f16x2 P  = z * (_Float16)(-5.70498872745e-3f) + (_Float16)(2.06390887954e-2f);
    P = z * P + (_Float16)(-5.37397155531e-2f);
    P = z * P + (_Float16)(1.33314422036e-1f);
    P = z * P + (_Float16)(-3.33332819422e-1f);
    f16x2 tc = cz * P + c16;          // tanh(c)
    PkU r; r.f = so * tc;             // h = sigma(o)*tanh(c), packed f16x2
    return r.u;
}

__global__ __launch_bounds__(256) void lstm_main(
    const float* __restrict__ in, const _Float16* __restrict__ Mb,
    const float* __restrict__ fb, const _Float16* __restrict__ decWb,
    const float* __restrict__ dec_b, float* __restrict__ out) {
    // tiny per-wave broadcast buffer (future-row fan-out only)
    __shared__ float fbc[4][32];

    const int lane = threadIdx.x & 63;
    const int w    = threadIdx.x >> 6;
    const int l16  = lane & 15;
    const int q    = lane >> 4;
    const int wave = blockIdx.x * 4 + w;      // 0..8191
    const int b    = wave >> 6;                // 64 waves per batch row
    const int t0   = (wave & 63) * 32;         // 0..2016 (unique rows only)

    // Input B-fragments: B[k=q*8+j][n=l16] = input[b][t][q*8+j]  (t < 2048)
    f16x8 bfr[2];
#pragma unroll
    for (int s = 0; s < 2; ++s) {
        int t  = t0 + s * 16 + l16;
        const float* p = in + ((size_t)(b * T_IN + t)) * FIN + q * 8;
        f32x4 u0 = *(const f32x4*)(p);
        f32x4 u1 = *(const f32x4*)(p + 4);
        f16x8 v;
#pragma unroll
        for (int j = 0; j < 4; ++j) { v[j] = (_Float16)u0[j]; v[4 + j] = (_Float16)u1[j]; }
        bfr[s] = v;
    }

    // decoder acc starts at dec_b (rides the MFMA C operand)
    f32x4 dacc[2][2];
#pragma unroll
    for (int ot = 0; ot < 2; ++ot) {
        f32x4 db = *(const f32x4*)(dec_b + ot * 16 + q * 4);
        dacc[0][ot] = db; dacc[1][ot] = db;
    }

    for (int hc = 0; hc < 8; ++hc) {
        const int hb = hc * 32;
        // Gate weight A-frags + bias C-frags
        f16x8 afr[3][2];
        f32x4 fbv[3][2];
#pragma unroll
        for (int gt = 0; gt < 3; ++gt)
#pragma unroll
            for (int X = 0; X < 2; ++X) {
                int grow = gt * 256 + hb + X * 16;
                afr[gt][X] = *(const f16x8*)(Mb + (size_t)(grow + l16) * 32 + q * 8);
                fbv[gt][X] = *(const f32x4*)(fb + grow + q * 4);
            }
        // Decoder A-frags (hid-permuted layout): A2[m=ot*16+l16][slot q*8+j]
        f16x8 a2[2];
#pragma unroll
        for (int ot = 0; ot < 2; ++ot)
            a2[ot] = *(const f16x8*)(decWb + (size_t)(ot * 16 + l16) * 256 + hb + q * 8);

#pragma unroll
        for (int s = 0; s < 2; ++s) {
            // D[m = gate hid][n = t]; bias pre-loaded as C operand.
            // Values arrive pre-scaled: exp2-ready.
            f32x4 gi[2], gg[2], go[2];
#pragma unroll
            for (int X = 0; X < 2; ++X) {
                gi[X] = __builtin_amdgcn_mfma_f32_16x16x32_f16(afr[0][X], bfr[s], fbv[0][X], 0, 0, 0);
                gg[X] = __builtin_amdgcn_mfma_f32_16x16x32_f16(afr[1][X], bfr[s], fbv[1][X], 0, 0, 0);
                go[X] = __builtin_amdgcn_mfma_f32_16x16x32_f16(afr[2][X], bfr[s], fbv[2][X], 0, 0, 0);
            }
            // Activation output in production order IS the decoder B-frag
            // (decWb slot permutation): elems 0..3 = X=0 r=0..3 (hid 4q+r),
            // elems 4..7 = X=1 r=0..3 (hid 16+4q+r).
            B2U b2u;
#pragma unroll
            for (int X = 0; X < 2; ++X) {
                f32x2 i01 = { gi[X][0], gi[X][1] }, i23 = { gi[X][2], gi[X][3] };
                f32x2 g01 = { gg[X][0], gg[X][1] }, g23 = { gg[X][2], gg[X][3] };
                f32x2 o01 = { go[X][0], go[X][1] }, o23 = { go[X][2], go[X][3] };
                b2u.u[X * 2 + 0] = act_pair(i01, g01, o01);
                b2u.u[X * 2 + 1] = act_pair(i23, g23, o23);
            }
#pragma unroll
            for (int ot = 0; ot < 2; ++ot)
                dacc[s][ot] = __builtin_amdgcn_mfma_f32_16x16x32_f16(a2[ot], b2u.v, dacc[s][ot], 0, 0, 0);
        }
    }

    // D2[od = ot*16 + 4q + r][t=l16] -> out[(b*TT+t)*32 + od], float4 per lane
#pragma unroll
    for (int s = 0; s < 2; ++s) {
        int t = t0 + s * 16 + l16;
        size_t ro = ((size_t)(b * TT + t)) * FOUT;
#pragma unroll
        for (int ot = 0; ot < 2; ++ot)
            *(f32x4*)(out + ro + ot * 16 + q * 4) = dacc[s][ot];
    }

    // Future rows 2048..2111 are copies of row 2047 (held by lanes l16==15
    // of the wave with t0==2016). Broadcast that row wave-internally via LDS,
    // then all 64 lanes fan the 64 duplicate rows out.
    if ((wave & 63) == 63) {
        float* fo = &fbc[w][0];
        if (l16 == 15) {
            *(f32x4*)(fo + q * 4)      = dacc[1][0];
            *(f32x4*)(fo + 16 + q * 4) = dacc[1][1];
        }
        asm volatile("s_waitcnt lgkmcnt(0)" ::: "memory");
        f32x4 r0 = *(const f32x4*)(fo + q * 4);
        f32x4 r1 = *(const f32x4*)(fo + 16 + q * 4);
#pragma unroll
        for (int fg = 0; fg < 4; ++fg) {
            int t = T_IN + fg * 16 + l16;
            size_t ro = ((size_t)(b * TT + t)) * FOUT;
            *(f32x4*)(out + ro + q * 4)      = r0;
            *(f32x4*)(out + ro + 16 + q * 4) = r1;
        }
    }
}

extern "C" void kernel_launch(void* const* d_in, const int* in_sizes, int n_in,
                              void* d_out, int out_size, void* d_ws, size_t ws_size,
                              hipStream_t stream) {
    const float* input = (const float*)d_in[0];
    const float* enc_W = (const float*)d_in[1];
    const float* enc_b = (const float*)d_in[2];
    const float* W_ih  = (const float*)d_in[3];
    // d_in[4] = W_hh: unused (h0 = 0 -> state_gates = b_hh only)
    const float* b_ih  = (const float*)d_in[5];
    const float* b_hh  = (const float*)d_in[6];
    const float* dec_W = (const float*)d_in[7];
    const float* dec_b = (const float*)d_in[8];
    // d_in[9] = future_n (fixed 64, baked into TT)

    _Float16* Mb    = (_Float16*)d_ws;
    float*    fb    = (float*)((char*)d_ws + WS_FB_OFF);
    _Float16* decWb = (_Float16*)((char*)d_ws + WS_DECW_OFF);
    float*    out   = (float*)d_out;

    prep2<<<776, 256, 0, stream>>>(enc_W, enc_b, W_ih, b_ih, b_hh, dec_W, Mb, fb, decWb);
    // 128 b * 2048 unique t rows / 32 rows-per-wave = 8192 waves; 4 waves/block
    // = 2048 blocks = exactly 8 blocks/CU (perfect balance)
    lstm_main<<<2048, 256, 0, stream>>>(input, Mb, fb, decWb, dec_b, out);
}